// Round 1
// baseline (2537.505 us; speedup 1.0000x reference)
//
#include <hip/hip_runtime.h>
#include <hip/hip_bf16.h>
#include <math.h>

#define HID 256
#define HEADS 8
#define KP0 512

typedef __attribute__((ext_vector_type(8))) short short8;
typedef __attribute__((ext_vector_type(4))) float floatx4;

__device__ __forceinline__ void gl_lds16(const void* g, void* l) {
  __builtin_amdgcn_global_load_lds(
      (const __attribute__((address_space(1))) void*)g,
      (__attribute__((address_space(3))) void*)l, 16, 0, 0);
}

__device__ __forceinline__ float blo(unsigned u) { return __uint_as_float(u << 16); }
__device__ __forceinline__ float bhi(unsigned u) { return __uint_as_float(u & 0xffff0000u); }

// ---------------- CSR build ----------------

__global__ __launch_bounds__(256) void deg_count_kernel(const int* __restrict__ ei,
    int* __restrict__ deg, int E, int Etot) {
  int idx = blockIdx.x * 256 + threadIdx.x;
  if (idx >= Etot) return;
  int d = (idx < E) ? ei[E + idx] : (idx - E);
  atomicAdd(&deg[d], 1);
}

__global__ __launch_bounds__(1024) void scan_kernel(const int* __restrict__ deg,
    int* __restrict__ rowptr, int* __restrict__ cursor, int N) {
  __shared__ int sums[1024];
  int t = threadIdx.x;
  int chunk = (N + 1023) / 1024;
  int lo = t * chunk, hi = min(N, lo + chunk);
  int s = 0;
  for (int i = lo; i < hi; ++i) s += deg[i];
  sums[t] = s;
  __syncthreads();
  for (int off = 1; off < 1024; off <<= 1) {
    int v = (t >= off) ? sums[t - off] : 0;
    __syncthreads();
    sums[t] += v;
    __syncthreads();
  }
  int prefix = (t == 0) ? 0 : sums[t - 1];
  for (int i = lo; i < hi; ++i) {
    rowptr[i] = prefix;
    cursor[i] = prefix;
    prefix += deg[i];
  }
  if (t == 1023) rowptr[N] = sums[1023];
}

__global__ __launch_bounds__(256) void scatter_kernel(const int* __restrict__ ei,
    int* __restrict__ cursor, int* __restrict__ csr_src, int E, int Etot) {
  int idx = blockIdx.x * 256 + threadIdx.x;
  if (idx >= Etot) return;
  int s, d;
  if (idx < E) { s = ei[idx]; d = ei[E + idx]; }
  else { s = idx - E; d = s; }
  int pos = atomicAdd(&cursor[d], 1);
  csr_src[pos] = s;
}

// ---------------- input conversions ----------------

__global__ __launch_bounds__(256) void conv_x_kernel(const float* __restrict__ x,
    __hip_bfloat16* __restrict__ xb, int M, int K) {
  int idx = blockIdx.x * 256 + threadIdx.x;
  if (idx >= M * KP0) return;
  int n = idx >> 9, k = idx & (KP0 - 1);
  xb[idx] = __float2bfloat16((k < K) ? x[(size_t)n * K + k] : 0.f);
}

__global__ __launch_bounds__(256) void convT_w_kernel(const float* __restrict__ W,
    __hip_bfloat16* __restrict__ Wt, int K, int Kp) {
  int idx = blockIdx.x * 256 + threadIdx.x;
  if (idx >= 256 * Kp) return;
  int n = idx / Kp, k = idx - n * Kp;
  Wt[idx] = __float2bfloat16((k < K) ? W[(size_t)k * 256 + n] : 0.f);
}

// ---------------- bf16 MFMA GEMM (m97-style): C[M,256] = A[Mp,Kp] @ Bt[256,Kp]^T ----

__global__ __launch_bounds__(256) void gemm_mfma(const __hip_bfloat16* __restrict__ A,
    const __hip_bfloat16* __restrict__ Bt, __hip_bfloat16* __restrict__ C,
    int M, int Kp) {
  __shared__ __align__(16) __hip_bfloat16 As[128][32];
  __shared__ __align__(16) __hip_bfloat16 Bs[128][32];
  int tid = threadIdx.x;
  int wave = tid >> 6, lane = tid & 63;
  int quad = lane >> 4, mr = lane & 15;
  int row0 = blockIdx.x * 128, col0 = blockIdx.y * 128;
  int wm = (wave & 1) * 64, wn = (wave >> 1) * 64;
  floatx4 acc[4][4] = {};

  int srow = (lane >> 2);
  int kslot = lane & 3;
  int kc = (kslot ^ (srow & 3)) * 8;

  for (int k0 = 0; k0 < Kp; k0 += 32) {
#pragma unroll
    for (int j = 0; j < 2; ++j) {
      int r = wave * 32 + j * 16 + srow;
      gl_lds16(A + (size_t)(row0 + r) * Kp + k0 + kc, &As[wave * 32 + j * 16][0]);
      gl_lds16(Bt + (size_t)(col0 + r) * Kp + k0 + kc, &Bs[wave * 32 + j * 16][0]);
    }
    __syncthreads();
    short8 af[4], bfr[4];
#pragma unroll
    for (int r = 0; r < 4; ++r) {
      int row = wm + r * 16 + mr;
      af[r] = *(const short8*)&As[row][(quad ^ (row & 3)) * 8];
      int col = wn + r * 16 + mr;
      bfr[r] = *(const short8*)&Bs[col][(quad ^ (col & 3)) * 8];
    }
#pragma unroll
    for (int r = 0; r < 4; ++r)
#pragma unroll
      for (int c = 0; c < 4; ++c)
        acc[r][c] = __builtin_amdgcn_mfma_f32_16x16x32_bf16(af[r], bfr[c], acc[r][c], 0, 0, 0);
    __syncthreads();
  }
#pragma unroll
  for (int r = 0; r < 4; ++r) {
#pragma unroll
    for (int c = 0; c < 4; ++c) {
#pragma unroll
      for (int i = 0; i < 4; ++i) {
        int row = row0 + wm + r * 16 + quad * 4 + i;
        int col = col0 + wn + c * 16 + mr;
        if (row < M) C[(size_t)row * HID + col] = __float2bfloat16(acc[r][c][i]);
      }
    }
  }
}

// ---------------- per-node attention logits (bf16 H, vectorized) ----------------

__global__ __launch_bounds__(256) void node_logits_kernel(const __hip_bfloat16* __restrict__ H,
    const float* __restrict__ a_src, const float* __restrict__ a_dst,
    float* __restrict__ en_src, float* __restrict__ en_dst, int N) {
  int idx = blockIdx.x * 256 + threadIdx.x;
  if (idx >= N * HEADS) return;
  int n = idx >> 3, h = idx & 7;
  const uint4* Hp = (const uint4*)(H + (size_t)n * HID + h * 32);
  const float* S = a_src + h * 32;
  const float* D = a_dst + h * 32;
  float es = 0.f, ed = 0.f;
#pragma unroll
  for (int j = 0; j < 4; ++j) {
    uint4 u = Hp[j];
    unsigned w[4] = {u.x, u.y, u.z, u.w};
#pragma unroll
    for (int p = 0; p < 4; ++p) {
      float lo = blo(w[p]);
      float hi = bhi(w[p]);
      int c = j * 8 + p * 2;
      es += lo * S[c] + hi * S[c + 1];
      ed += lo * D[c] + hi * D[c + 1];
    }
  }
  en_src[idx] = es;
  en_dst[idx] = ed;
}

// ---------------- fused single-pass online-softmax aggregation ----------------
// One wave per dst node. Lane roles:
//   eo = lane>>5   : which edge of a pair (16B paired row gathers)
//   cg = lane&31   : channel group -> channels cg*8 .. cg*8+7 (head cg>>2)
//   (h_ld,j_ld) = (lane>>3, lane&7): en_src loader role (edge j, head h)
// Per 64-edge block: 1 csr load -> 8 batched en gathers -> 4 groups of 16 edges,
// each group: shfl-distribute logits, one deferred-max rescale, 8 paired uint4
// row gathers + weighted bf16 accumulate. Exact online softmax (no THR).

__global__ __launch_bounds__(256) void gat_agg_kernel(const __hip_bfloat16* __restrict__ H,
    const float* __restrict__ en_src, const float* __restrict__ en_dst,
    const int* __restrict__ rowptr, const int* __restrict__ csr_src,
    const float* __restrict__ bias, float* __restrict__ out,
    __hip_bfloat16* __restrict__ hb, int apply_elu, int N) {
  int wave = threadIdx.x >> 6;
  int lane = threadIdx.x & 63;
  int n = blockIdx.x * 4 + wave;
  if (n >= N) return;
  int eo = lane >> 5;
  int cg = lane & 31;
  int h_own = cg >> 2;
  int h_ld = lane >> 3;
  int j_ld = lane & 7;

  int beg = rowptr[n], end = rowptr[n + 1];
  float ed_ld = en_dst[n * HEADS + h_ld];

  float m = -1e30f, s = 0.f;
  float acc[8] = {0.f, 0.f, 0.f, 0.f, 0.f, 0.f, 0.f, 0.f};
  const __hip_bfloat16* Hc = H + cg * 8;

  for (int cs = beg; cs < end; cs += 64) {
    int cnt = min(64, end - cs);
    int myidx = csr_src[cs + ((lane < cnt) ? lane : (cnt - 1))];

    // batched en_src gather: edge k*8+j_ld, head h_ld -> leaky logit
    float en_all[8];
#pragma unroll
    for (int k = 0; k < 8; ++k) {
      int sk = __shfl(myidx, k * 8 + j_ld);
      float ev = -1e30f;
      if (k * 8 + j_ld < cnt) ev = en_src[sk * HEADS + h_ld] + ed_ld;
      en_all[k] = (ev > 0.f) ? ev : 0.2f * ev;
    }

#pragma unroll
    for (int g = 0; g < 4; ++g) {
      int gb = g * 16;
      if (gb >= cnt) break;
      float eA = en_all[2 * g];
      float eB = en_all[2 * g + 1];
      // distribute logits for my head: va[j] = logit(edge gb+j, head h_own)
      float va[16];
#pragma unroll
      for (int j = 0; j < 8; ++j) {
        va[j] = __shfl(eA, (h_own << 3) | j);
        va[8 + j] = __shfl(eB, (h_own << 3) | j);
      }
      float cm = va[0];
#pragma unroll
      for (int j = 1; j < 16; ++j) cm = fmaxf(cm, va[j]);
      float mn = fmaxf(m, cm);
      float r = __expf(m - mn);
      m = mn;
      s *= r;
#pragma unroll
      for (int i = 0; i < 8; ++i) acc[i] *= r;
#pragma unroll
      for (int p = 0; p < 8; ++p) {
        int sp = __shfl(myidx, gb + 2 * p + eo);
        const uint4 gv = *(const uint4*)(Hc + (size_t)sp * HID);
        float vv = eo ? va[2 * p + 1] : va[2 * p];
        float w = __expf(vv - m);
        s += w;
        acc[0] += w * blo(gv.x);
        acc[1] += w * bhi(gv.x);
        acc[2] += w * blo(gv.y);
        acc[3] += w * bhi(gv.y);
        acc[4] += w * blo(gv.z);
        acc[5] += w * bhi(gv.z);
        acc[6] += w * blo(gv.w);
        acc[7] += w * bhi(gv.w);
      }
    }
  }

  // combine the two edge-halves
  float s_tot = s + __shfl_xor(s, 32);
  float rs = 1.f / (s_tot + 1e-16f);
#pragma unroll
  for (int i = 0; i < 8; ++i) acc[i] += __shfl_xor(acc[i], 32);
  float a0 = eo ? acc[4] : acc[0];
  float a1 = eo ? acc[5] : acc[1];
  float a2 = eo ? acc[6] : acc[2];
  float a3 = eo ? acc[7] : acc[3];
  int cb4 = cg * 8 + eo * 4;
  float4 bv = *(const float4*)(bias + cb4);
  float4 o;
  o.x = a0 * rs + bv.x;
  o.y = a1 * rs + bv.y;
  o.z = a2 * rs + bv.z;
  o.w = a3 * rs + bv.w;
  if (apply_elu) {
    o.x = (o.x > 0.f) ? o.x : expm1f(o.x);
    o.y = (o.y > 0.f) ? o.y : expm1f(o.y);
    o.z = (o.z > 0.f) ? o.z : expm1f(o.z);
    o.w = (o.w > 0.f) ? o.w : expm1f(o.w);
  }
  *(float4*)(out + (size_t)n * HID + cb4) = o;
  union { __hip_bfloat16 hh[4]; uint2 u; } pk;
  pk.hh[0] = __float2bfloat16(o.x);
  pk.hh[1] = __float2bfloat16(o.y);
  pk.hh[2] = __float2bfloat16(o.z);
  pk.hh[3] = __float2bfloat16(o.w);
  *(uint2*)(hb + (size_t)n * HID + cb4) = pk.u;
}

// ---------------- JK max + final linear + log_softmax ----------------

__global__ __launch_bounds__(256) void final_kernel(const float* __restrict__ h0,
    const float* __restrict__ h1, const float* __restrict__ h2,
    const float* __restrict__ Wf, const float* __restrict__ bf,
    float* __restrict__ out, int N) {
  __shared__ float Wfs[HID * 40];
  __shared__ float jks[4][HID];
  int tid = threadIdx.x;
  for (int i = tid; i < HID * 40; i += 256) Wfs[i] = Wf[i];
  int sub = tid >> 6, lane = tid & 63;
  int n = blockIdx.x * 4 + sub;
  if (n < N) {
    const float4* p0 = (const float4*)(h0 + (size_t)n * HID);
    const float4* p1 = (const float4*)(h1 + (size_t)n * HID);
    const float4* p2 = (const float4*)(h2 + (size_t)n * HID);
    float4 a = p0[lane], b = p1[lane], cc = p2[lane];
    float4 r;
    r.x = fmaxf(fmaxf(a.x, b.x), cc.x);
    r.y = fmaxf(fmaxf(a.y, b.y), cc.y);
    r.z = fmaxf(fmaxf(a.z, b.z), cc.z);
    r.w = fmaxf(fmaxf(a.w, b.w), cc.w);
    *(float4*)&jks[sub][lane * 4] = r;
  }
  __syncthreads();
  float logit = -INFINITY;
  if (lane < 40 && n < N) {
    float accv = bf[lane];
#pragma unroll 8
    for (int k = 0; k < HID; ++k) accv += jks[sub][k] * Wfs[k * 40 + lane];
    logit = accv;
  }
  float mx = logit;
#pragma unroll
  for (int off = 32; off > 0; off >>= 1) mx = fmaxf(mx, __shfl_down(mx, off));
  mx = __shfl(mx, 0);
  float ex = (lane < 40 && n < N) ? __expf(logit - mx) : 0.f;
  float sm = ex;
#pragma unroll
  for (int off = 32; off > 0; off >>= 1) sm += __shfl_down(sm, off);
  sm = __shfl(sm, 0);
  if (lane < 40 && n < N) out[(size_t)n * 40 + lane] = logit - mx - __logf(sm);
}

// ---------------- launch ----------------

extern "C" void kernel_launch(void* const* d_in, const int* in_sizes, int n_in,
                              void* d_out, int out_size, void* d_ws, size_t ws_size,
                              hipStream_t stream) {
  (void)n_in; (void)out_size; (void)ws_size;
  const float* x   = (const float*)d_in[0];
  const int*   ei  = (const int*)d_in[1];
  const float* W0  = (const float*)d_in[2];
  const float* as0 = (const float*)d_in[3];
  const float* ad0 = (const float*)d_in[4];
  const float* b0  = (const float*)d_in[5];
  const float* W1  = (const float*)d_in[6];
  const float* as1 = (const float*)d_in[7];
  const float* ad1 = (const float*)d_in[8];
  const float* b1  = (const float*)d_in[9];
  const float* W2  = (const float*)d_in[10];
  const float* as2 = (const float*)d_in[11];
  const float* ad2 = (const float*)d_in[12];
  const float* b2  = (const float*)d_in[13];
  const float* Wf  = (const float*)d_in[14];
  const float* bf  = (const float*)d_in[15];
  float* out = (float*)d_out;

  const int E = in_sizes[1] / 2;
  const int IN_CH = in_sizes[2] / HID;      // 500
  const int N = in_sizes[0] / IN_CH;        // 100000
  const int Etot = E + N;
  const int Mp = ((N + 127) / 128) * 128;   // 100096
  const size_t NM = (size_t)N * HID;

  __hip_bfloat16* xb  = (__hip_bfloat16*)d_ws;            // Mp*KP0
  __hip_bfloat16* Htb = xb + (size_t)Mp * KP0;            // N*HID
  __hip_bfloat16* hb  = Htb + NM;                         // Mp*HID
  __hip_bfloat16* Wt0 = hb + (size_t)Mp * HID;            // 256*KP0
  __hip_bfloat16* Wt1 = Wt0 + 256 * KP0;                  // 256*256
  __hip_bfloat16* Wt2 = Wt1 + 256 * 256;
  float* fbase = (float*)(Wt2 + 256 * 256);
  float* h0   = fbase;
  float* h1   = fbase + NM;
  float* h2   = fbase + 2 * NM;
  float* en_s = fbase + 3 * NM;
  float* en_d = en_s + (size_t)N * HEADS;
  int* rowptr  = (int*)(en_d + (size_t)N * HEADS);
  int* deg     = rowptr + (N + 1);
  int* cursor  = deg + N;
  int* csr_src = cursor + N;

  hipMemsetAsync(deg, 0, sizeof(int) * N, stream);
  int ebl = (Etot + 255) / 256;
  deg_count_kernel<<<ebl, 256, 0, stream>>>(ei, deg, E, Etot);
  scan_kernel<<<1, 1024, 0, stream>>>(deg, rowptr, cursor, N);
  scatter_kernel<<<ebl, 256, 0, stream>>>(ei, cursor, csr_src, E, Etot);

  conv_x_kernel<<<((size_t)N * KP0 + 255) / 256, 256, 0, stream>>>(x, xb, N, IN_CH);
  convT_w_kernel<<<(256 * KP0 + 255) / 256, 256, 0, stream>>>(W0, Wt0, IN_CH, KP0);
  convT_w_kernel<<<(256 * 256 + 255) / 256, 256, 0, stream>>>(W1, Wt1, HID, HID);
  convT_w_kernel<<<(256 * 256 + 255) / 256, 256, 0, stream>>>(W2, Wt2, HID, HID);

  dim3 ggrid(Mp / 128, 2);
  int lblocks = (N * HEADS + 255) / 256;
  int ablocks = (N + 3) / 4;

  // layer 0
  gemm_mfma<<<ggrid, 256, 0, stream>>>(xb, Wt0, Htb, N, KP0);
  node_logits_kernel<<<lblocks, 256, 0, stream>>>(Htb, as0, ad0, en_s, en_d, N);
  gat_agg_kernel<<<ablocks, 256, 0, stream>>>(Htb, en_s, en_d, rowptr, csr_src, b0, h0, hb, 1, N);
  // layer 1
  gemm_mfma<<<ggrid, 256, 0, stream>>>(hb, Wt1, Htb, N, HID);
  node_logits_kernel<<<lblocks, 256, 0, stream>>>(Htb, as1, ad1, en_s, en_d, N);
  gat_agg_kernel<<<ablocks, 256, 0, stream>>>(Htb, en_s, en_d, rowptr, csr_src, b1, h1, hb, 1, N);
  // layer 2
  gemm_mfma<<<ggrid, 256, 0, stream>>>(hb, Wt2, Htb, N, HID);
  node_logits_kernel<<<lblocks, 256, 0, stream>>>(Htb, as2, ad2, en_s, en_d, N);
  gat_agg_kernel<<<ablocks, 256, 0, stream>>>(Htb, en_s, en_d, rowptr, csr_src, b2, h2, hb, 0, N);

  final_kernel<<<(N + 3) / 4, 256, 0, stream>>>(h0, h1, h2, Wf, bf, out, N);
}

// Round 2
// 2516.688 us; speedup vs baseline: 1.0083x; 1.0083x over previous
//
#include <hip/hip_runtime.h>
#include <hip/hip_bf16.h>
#include <math.h>

#define HID 256
#define HEADS 8
#define KP0 512
#define BCAP 8192   // bucket capacity (mean ~4225 for uniform random; overflow ~impossible)

typedef __attribute__((ext_vector_type(8))) short short8;
typedef __attribute__((ext_vector_type(4))) float floatx4;

__device__ __forceinline__ void gl_lds16(const void* g, void* l) {
  __builtin_amdgcn_global_load_lds(
      (const __attribute__((address_space(1))) void*)g,
      (__attribute__((address_space(3))) void*)l, 16, 0, 0);
}

// ---------------- bucketed CSR build ----------------
// bucket b = dst >> 7 (128 nodes per bucket). Staged entry: (d&127)<<17 | s.

__global__ __launch_bounds__(256) void bucket_partition_kernel(const int* __restrict__ ei,
    int* __restrict__ bcnt, unsigned* __restrict__ stag, int E, int Etot) {
  int idx = blockIdx.x * 256 + threadIdx.x;
  if (idx >= Etot) return;
  int s, d;
  if (idx < E) { s = ei[idx]; d = ei[E + idx]; }
  else { s = idx - E; d = s; }
  int b = d >> 7;
  int pos = atomicAdd(&bcnt[b], 1);
  if (pos < BCAP) stag[(size_t)b * BCAP + pos] = ((unsigned)(d & 127) << 17) | (unsigned)s;
}

__global__ __launch_bounds__(1024) void bucket_scan_kernel(const int* __restrict__ bcnt,
    int* __restrict__ base, int NB) {
  __shared__ int sums[1024];
  int t = threadIdx.x;
  int chunk = (NB + 1023) / 1024;
  int lo = t * chunk, hi = min(NB, lo + chunk);
  int s = 0;
  for (int i = lo; i < hi; ++i) s += min(bcnt[i], BCAP);
  sums[t] = s;
  __syncthreads();
  for (int off = 1; off < 1024; off <<= 1) {
    int v = (t >= off) ? sums[t - off] : 0;
    __syncthreads();
    sums[t] += v;
    __syncthreads();
  }
  int prefix = (t == 0) ? 0 : sums[t - 1];
  for (int i = lo; i < hi; ++i) {
    base[i] = prefix;
    prefix += min(bcnt[i], BCAP);
  }
  if (t == 1023) base[NB] = sums[1023];
}

// one block per bucket: LDS degree histogram -> prefix -> scatter into contiguous window
__global__ __launch_bounds__(256) void bucket_build_kernel(const unsigned* __restrict__ stag,
    const int* __restrict__ bcnt, const int* __restrict__ base,
    int* __restrict__ rowptr, int* __restrict__ csr_src, int N) {
  __shared__ int deg[128], pfx[128], cur[128];
  int b = blockIdx.x;
  int t = threadIdx.x;
  int cnt = min(bcnt[b], BCAP);
  int gbase = base[b];
  int node0 = b << 7;
  int nn = min(128, N - node0);
  if (t < 128) deg[t] = 0;
  __syncthreads();
  const unsigned* sb = stag + (size_t)b * BCAP;
  for (int i = t; i < cnt; i += 256) atomicAdd(&deg[sb[i] >> 17], 1);
  __syncthreads();
  if (t == 0) {
    int run = 0;
#pragma unroll 8
    for (int i = 0; i < 128; ++i) { pfx[i] = run; run += deg[i]; }
  }
  __syncthreads();
  if (t < 128) cur[t] = pfx[t];
  if (t < nn) rowptr[node0 + t] = gbase + pfx[t];
  if (b == (int)gridDim.x - 1 && t == 0) rowptr[N] = gbase + cnt;
  __syncthreads();
  for (int i = t; i < cnt; i += 256) {
    unsigned v = sb[i];
    int dl = v >> 17;
    int pos = gbase + atomicAdd(&cur[dl], 1);
    csr_src[pos] = (int)(v & 0x1ffff);
  }
}

// ---------------- input conversions ----------------

__global__ __launch_bounds__(256) void conv_x_kernel(const float* __restrict__ x,
    __hip_bfloat16* __restrict__ xb, int M, int K) {
  int idx = blockIdx.x * 256 + threadIdx.x;
  if (idx >= M * KP0) return;
  int n = idx >> 9, k = idx & (KP0 - 1);
  xb[idx] = __float2bfloat16((k < K) ? x[(size_t)n * K + k] : 0.f);
}

__global__ __launch_bounds__(256) void convT_w_kernel(const float* __restrict__ W,
    __hip_bfloat16* __restrict__ Wt, int K, int Kp) {
  int idx = blockIdx.x * 256 + threadIdx.x;
  if (idx >= 256 * Kp) return;
  int n = idx / Kp, k = idx - n * Kp;
  Wt[idx] = __float2bfloat16((k < K) ? W[(size_t)k * 256 + n] : 0.f);
}

// ---------------- bf16 MFMA GEMM (m97-style): C[M,256] = A[Mp,Kp] @ Bt[256,Kp]^T ----

__global__ __launch_bounds__(256) void gemm_mfma(const __hip_bfloat16* __restrict__ A,
    const __hip_bfloat16* __restrict__ Bt, __hip_bfloat16* __restrict__ C,
    int M, int Kp) {
  __shared__ __align__(16) __hip_bfloat16 As[128][32];
  __shared__ __align__(16) __hip_bfloat16 Bs[128][32];
  int tid = threadIdx.x;
  int wave = tid >> 6, lane = tid & 63;
  int quad = lane >> 4, mr = lane & 15;
  int row0 = blockIdx.x * 128, col0 = blockIdx.y * 128;
  int wm = (wave & 1) * 64, wn = (wave >> 1) * 64;
  floatx4 acc[4][4] = {};

  int srow = (lane >> 2);
  int kslot = lane & 3;
  int kc = (kslot ^ (srow & 3)) * 8;

  for (int k0 = 0; k0 < Kp; k0 += 32) {
#pragma unroll
    for (int j = 0; j < 2; ++j) {
      int r = wave * 32 + j * 16 + srow;
      gl_lds16(A + (size_t)(row0 + r) * Kp + k0 + kc, &As[wave * 32 + j * 16][0]);
      gl_lds16(Bt + (size_t)(col0 + r) * Kp + k0 + kc, &Bs[wave * 32 + j * 16][0]);
    }
    __syncthreads();
    short8 af[4], bfr[4];
#pragma unroll
    for (int r = 0; r < 4; ++r) {
      int row = wm + r * 16 + mr;
      af[r] = *(const short8*)&As[row][(quad ^ (row & 3)) * 8];
      int col = wn + r * 16 + mr;
      bfr[r] = *(const short8*)&Bs[col][(quad ^ (col & 3)) * 8];
    }
#pragma unroll
    for (int r = 0; r < 4; ++r)
#pragma unroll
      for (int c = 0; c < 4; ++c)
        acc[r][c] = __builtin_amdgcn_mfma_f32_16x16x32_bf16(af[r], bfr[c], acc[r][c], 0, 0, 0);
    __syncthreads();
  }
#pragma unroll
  for (int r = 0; r < 4; ++r) {
#pragma unroll
    for (int c = 0; c < 4; ++c) {
#pragma unroll
      for (int i = 0; i < 4; ++i) {
        int row = row0 + wm + r * 16 + quad * 4 + i;
        int col = col0 + wn + c * 16 + mr;
        if (row < M) C[(size_t)row * HID + col] = __float2bfloat16(acc[r][c][i]);
      }
    }
  }
}

// ---------------- per-node attention logits (bf16 H, vectorized) ----------------

__global__ __launch_bounds__(256) void node_logits_kernel(const __hip_bfloat16* __restrict__ H,
    const float* __restrict__ a_src, const float* __restrict__ a_dst,
    float* __restrict__ en_src, float* __restrict__ en_dst, int N) {
  int idx = blockIdx.x * 256 + threadIdx.x;
  if (idx >= N * HEADS) return;
  int n = idx >> 3, h = idx & 7;
  const uint4* Hp = (const uint4*)(H + (size_t)n * HID + h * 32);
  const float* S = a_src + h * 32;
  const float* D = a_dst + h * 32;
  float es = 0.f, ed = 0.f;
#pragma unroll
  for (int j = 0; j < 4; ++j) {
    uint4 u = Hp[j];
    unsigned w[4] = {u.x, u.y, u.z, u.w};
#pragma unroll
    for (int p = 0; p < 4; ++p) {
      float lo = __uint_as_float(w[p] << 16);
      float hi = __uint_as_float(w[p] & 0xffff0000u);
      int c = j * 8 + p * 2;
      es += lo * S[c] + hi * S[c + 1];
      ed += lo * D[c] + hi * D[c + 1];
    }
  }
  en_src[idx] = es;
  en_dst[idx] = ed;
}

// ---------------- fused stats + aggregation: one wave per dst node ----------------

__global__ __launch_bounds__(256) void gat_agg_kernel(const __hip_bfloat16* __restrict__ H,
    const float* __restrict__ en_src, const float* __restrict__ en_dst,
    const int* __restrict__ rowptr, const int* __restrict__ csr_src,
    const float* __restrict__ bias, float* __restrict__ out,
    __hip_bfloat16* __restrict__ hb, int apply_elu, int N) {
  int wave = threadIdx.x >> 6;
  int lane = threadIdx.x & 63;
  int n = blockIdx.x * 4 + wave;
  if (n >= N) return;
  int h = lane >> 3;
  int slot = lane & 7;
  int beg = rowptr[n], end = rowptr[n + 1];
  float ed = en_dst[n * HEADS + h];

  float m = -1e30f, s = 0.f;
  for (int e = beg + slot; e < end; e += 8) {
    int src = csr_src[e];
    float v = en_src[src * HEADS + h] + ed;
    v = (v > 0.f) ? v : 0.2f * v;
    float mn = fmaxf(m, v);
    s = s * __expf(m - mn) + __expf(v - mn);
    m = mn;
  }
#pragma unroll
  for (int off = 1; off < 8; off <<= 1) {
    float mo = __shfl_xor(m, off);
    float so = __shfl_xor(s, off);
    float mn = fmaxf(m, mo);
    s = s * __expf(m - mn) + so * __expf(mo - mn);
    m = mn;
  }
  float rs = 1.f / (s + 1e-16f);

  float4 acc = {0.f, 0.f, 0.f, 0.f};
  const __hip_bfloat16* Hc = H + lane * 4;
  for (int cs = beg; cs < end; cs += 64) {
    int cnt = min(64, end - cs);
    int myidx = csr_src[cs + ((lane < cnt) ? lane : (cnt - 1))];
    int i = 0;
    for (; i + 4 <= cnt; i += 4) {
      int s0 = __shfl(myidx, i);
      int s1 = __shfl(myidx, i + 1);
      int s2 = __shfl(myidx, i + 2);
      int s3 = __shfl(myidx, i + 3);
      uint2 g0 = *(const uint2*)(Hc + (size_t)s0 * HID);
      uint2 g1 = *(const uint2*)(Hc + (size_t)s1 * HID);
      uint2 g2 = *(const uint2*)(Hc + (size_t)s2 * HID);
      uint2 g3 = *(const uint2*)(Hc + (size_t)s3 * HID);
      float e0 = en_src[s0 * HEADS + h];
      float e1 = en_src[s1 * HEADS + h];
      float e2 = en_src[s2 * HEADS + h];
      float e3 = en_src[s3 * HEADS + h];
      uint2 gs[4] = {g0, g1, g2, g3};
      float es4[4] = {e0, e1, e2, e3};
#pragma unroll
      for (int j = 0; j < 4; ++j) {
        float v = es4[j] + ed;
        v = (v > 0.f) ? v : 0.2f * v;
        float w = __expf(v - m) * rs;
        uint2 g = gs[j];
        acc.x += w * __uint_as_float(g.x << 16);
        acc.y += w * __uint_as_float(g.x & 0xffff0000u);
        acc.z += w * __uint_as_float(g.y << 16);
        acc.w += w * __uint_as_float(g.y & 0xffff0000u);
      }
    }
    for (; i < cnt; ++i) {
      int s0 = __shfl(myidx, i);
      uint2 g = *(const uint2*)(Hc + (size_t)s0 * HID);
      float v = en_src[s0 * HEADS + h] + ed;
      v = (v > 0.f) ? v : 0.2f * v;
      float w = __expf(v - m) * rs;
      acc.x += w * __uint_as_float(g.x << 16);
      acc.y += w * __uint_as_float(g.x & 0xffff0000u);
      acc.z += w * __uint_as_float(g.y << 16);
      acc.w += w * __uint_as_float(g.y & 0xffff0000u);
    }
  }
  float4 bv = *(const float4*)(bias + lane * 4);
  float4 o;
  o.x = acc.x + bv.x; o.y = acc.y + bv.y; o.z = acc.z + bv.z; o.w = acc.w + bv.w;
  if (apply_elu) {
    o.x = (o.x > 0.f) ? o.x : expm1f(o.x);
    o.y = (o.y > 0.f) ? o.y : expm1f(o.y);
    o.z = (o.z > 0.f) ? o.z : expm1f(o.z);
    o.w = (o.w > 0.f) ? o.w : expm1f(o.w);
  }
  *(float4*)(out + (size_t)n * HID + lane * 4) = o;
  union { __hip_bfloat16 hh[4]; uint2 u; } pk;
  pk.hh[0] = __float2bfloat16(o.x);
  pk.hh[1] = __float2bfloat16(o.y);
  pk.hh[2] = __float2bfloat16(o.z);
  pk.hh[3] = __float2bfloat16(o.w);
  *(uint2*)(hb + (size_t)n * HID + lane * 4) = pk.u;
}

// ---------------- JK max + final linear + log_softmax ----------------

__global__ __launch_bounds__(256) void final_kernel(const float* __restrict__ h0,
    const float* __restrict__ h1, const float* __restrict__ h2,
    const float* __restrict__ Wf, const float* __restrict__ bf,
    float* __restrict__ out, int N) {
  __shared__ float Wfs[HID * 40];
  __shared__ float jks[4][HID];
  int tid = threadIdx.x;
  for (int i = tid; i < HID * 40; i += 256) Wfs[i] = Wf[i];
  int sub = tid >> 6, lane = tid & 63;
  int n = blockIdx.x * 4 + sub;
  if (n < N) {
    const float4* p0 = (const float4*)(h0 + (size_t)n * HID);
    const float4* p1 = (const float4*)(h1 + (size_t)n * HID);
    const float4* p2 = (const float4*)(h2 + (size_t)n * HID);
    float4 a = p0[lane], b = p1[lane], cc = p2[lane];
    float4 r;
    r.x = fmaxf(fmaxf(a.x, b.x), cc.x);
    r.y = fmaxf(fmaxf(a.y, b.y), cc.y);
    r.z = fmaxf(fmaxf(a.z, b.z), cc.z);
    r.w = fmaxf(fmaxf(a.w, b.w), cc.w);
    *(float4*)&jks[sub][lane * 4] = r;
  }
  __syncthreads();
  float logit = -INFINITY;
  if (lane < 40 && n < N) {
    float accv = bf[lane];
#pragma unroll 8
    for (int k = 0; k < HID; ++k) accv += jks[sub][k] * Wfs[k * 40 + lane];
    logit = accv;
  }
  float mx = logit;
#pragma unroll
  for (int off = 32; off > 0; off >>= 1) mx = fmaxf(mx, __shfl_down(mx, off));
  mx = __shfl(mx, 0);
  float ex = (lane < 40 && n < N) ? __expf(logit - mx) : 0.f;
  float sm = ex;
#pragma unroll
  for (int off = 32; off > 0; off >>= 1) sm += __shfl_down(sm, off);
  sm = __shfl(sm, 0);
  if (lane < 40 && n < N) out[(size_t)n * 40 + lane] = logit - mx - __logf(sm);
}

// ---------------- launch ----------------

extern "C" void kernel_launch(void* const* d_in, const int* in_sizes, int n_in,
                              void* d_out, int out_size, void* d_ws, size_t ws_size,
                              hipStream_t stream) {
  (void)n_in; (void)out_size; (void)ws_size;
  const float* x   = (const float*)d_in[0];
  const int*   ei  = (const int*)d_in[1];
  const float* W0  = (const float*)d_in[2];
  const float* as0 = (const float*)d_in[3];
  const float* ad0 = (const float*)d_in[4];
  const float* b0  = (const float*)d_in[5];
  const float* W1  = (const float*)d_in[6];
  const float* as1 = (const float*)d_in[7];
  const float* ad1 = (const float*)d_in[8];
  const float* b1  = (const float*)d_in[9];
  const float* W2  = (const float*)d_in[10];
  const float* as2 = (const float*)d_in[11];
  const float* ad2 = (const float*)d_in[12];
  const float* b2  = (const float*)d_in[13];
  const float* Wf  = (const float*)d_in[14];
  const float* bf  = (const float*)d_in[15];
  float* out = (float*)d_out;

  const int E = in_sizes[1] / 2;
  const int IN_CH = in_sizes[2] / HID;      // 500
  const int N = in_sizes[0] / IN_CH;        // 100000
  const int Etot = E + N;
  const int Mp = ((N + 127) / 128) * 128;   // 100096
  const int NB = (N + 127) >> 7;            // buckets of 128 dst nodes
  const size_t NM = (size_t)N * HID;

  __hip_bfloat16* xb  = (__hip_bfloat16*)d_ws;            // Mp*KP0
  __hip_bfloat16* Htb = xb + (size_t)Mp * KP0;            // N*HID
  __hip_bfloat16* hb  = Htb + NM;                         // Mp*HID
  __hip_bfloat16* Wt0 = hb + (size_t)Mp * HID;            // 256*KP0
  __hip_bfloat16* Wt1 = Wt0 + 256 * KP0;                  // 256*256
  __hip_bfloat16* Wt2 = Wt1 + 256 * 256;
  float* fbase = (float*)(Wt2 + 256 * 256);
  float* h0   = fbase;
  float* h1   = fbase + NM;
  float* h2   = fbase + 2 * NM;
  float* en_s = fbase + 3 * NM;
  float* en_d = en_s + (size_t)N * HEADS;
  int* rowptr  = (int*)(en_d + (size_t)N * HEADS);        // N+1
  int* csr_src = rowptr + (N + 1);                        // Etot
  int* bcnt    = csr_src + Etot;                          // NB+1
  int* bbase   = bcnt + NB + 1;                           // NB+1
  unsigned* stag = (unsigned*)(bbase + NB + 1);           // NB*BCAP

  hipMemsetAsync(bcnt, 0, sizeof(int) * (NB + 1), stream);
  int ebl = (Etot + 255) / 256;
  bucket_partition_kernel<<<ebl, 256, 0, stream>>>(ei, bcnt, stag, E, Etot);
  bucket_scan_kernel<<<1, 1024, 0, stream>>>(bcnt, bbase, NB);
  bucket_build_kernel<<<NB, 256, 0, stream>>>(stag, bcnt, bbase, rowptr, csr_src, N);

  conv_x_kernel<<<((size_t)N * KP0 + 255) / 256, 256, 0, stream>>>(x, xb, N, IN_CH);
  convT_w_kernel<<<(256 * KP0 + 255) / 256, 256, 0, stream>>>(W0, Wt0, IN_CH, KP0);
  convT_w_kernel<<<(256 * 256 + 255) / 256, 256, 0, stream>>>(W1, Wt1, HID, HID);
  convT_w_kernel<<<(256 * 256 + 255) / 256, 256, 0, stream>>>(W2, Wt2, HID, HID);

  dim3 ggrid(Mp / 128, 2);
  int lblocks = (N * HEADS + 255) / 256;
  int ablocks = (N + 3) / 4;

  // layer 0
  gemm_mfma<<<ggrid, 256, 0, stream>>>(xb, Wt0, Htb, N, KP0);
  node_logits_kernel<<<lblocks, 256, 0, stream>>>(Htb, as0, ad0, en_s, en_d, N);
  gat_agg_kernel<<<ablocks, 256, 0, stream>>>(Htb, en_s, en_d, rowptr, csr_src, b0, h0, hb, 1, N);
  // layer 1
  gemm_mfma<<<ggrid, 256, 0, stream>>>(hb, Wt1, Htb, N, HID);
  node_logits_kernel<<<lblocks, 256, 0, stream>>>(Htb, as1, ad1, en_s, en_d, N);
  gat_agg_kernel<<<ablocks, 256, 0, stream>>>(Htb, en_s, en_d, rowptr, csr_src, b1, h1, hb, 1, N);
  // layer 2
  gemm_mfma<<<ggrid, 256, 0, stream>>>(hb, Wt2, Htb, N, HID);
  node_logits_kernel<<<lblocks, 256, 0, stream>>>(Htb, as2, ad2, en_s, en_d, N);
  gat_agg_kernel<<<ablocks, 256, 0, stream>>>(Htb, en_s, en_d, rowptr, csr_src, b2, h2, hb, 0, N);

  final_kernel<<<(N + 3) / 4, 256, 0, stream>>>(h0, h1, h2, Wf, bf, out, N);
}

// Round 3
// 2058.633 us; speedup vs baseline: 1.2326x; 1.2225x over previous
//
#include <hip/hip_runtime.h>
#include <hip/hip_bf16.h>
#include <math.h>

#define HID 256
#define HEADS 8
#define KP0 512
#define EPB 16384      // edges per block in hist/scatter passes
#define NBMAX 1024     // max buckets (N/128 = 782 here)

typedef __attribute__((ext_vector_type(8))) short short8;
typedef __attribute__((ext_vector_type(4))) float floatx4;

__device__ __forceinline__ void gl_lds16(const void* g, void* l) {
  __builtin_amdgcn_global_load_lds(
      (const __attribute__((address_space(1))) void*)g,
      (__attribute__((address_space(3))) void*)l, 16, 0, 0);
}

// ---------------- contention-free bucketed CSR build ----------------
// bucket b = dst >> 7 (128 nodes/bucket). Two-pass counting sort:
// per-block LDS histograms -> global exclusive scan (bucket-major, block-minor)
// -> scatter into private ranges (no global atomics anywhere).

__global__ __launch_bounds__(256) void edge_hist_kernel(const int* __restrict__ ei,
    int* __restrict__ F, int E, int Etot, int NB, int NBLK) {
  __shared__ int hist[NBMAX];
  int blk = blockIdx.x, t = threadIdx.x;
  for (int i = t; i < NBMAX; i += 256) hist[i] = 0;
  __syncthreads();
  int base = blk * EPB;
  int lim = min(EPB, Etot - base);
  for (int i = t; i < lim; i += 256) {
    int idx = base + i;
    int d = (idx < E) ? ei[E + idx] : (idx - E);
    atomicAdd(&hist[d >> 7], 1);
  }
  __syncthreads();
  for (int b = t; b < NB; b += 256) F[b * NBLK + blk] = hist[b];
}

__global__ __launch_bounds__(1024) void scanF_kernel(const int* __restrict__ F,
    int* __restrict__ S, int L) {
  __shared__ int sums[1024];
  int t = threadIdx.x;
  int chunk = (L + 1023) / 1024;
  int lo = t * chunk, hi = min(L, lo + chunk);
  int s = 0;
  for (int i = lo; i < hi; ++i) s += F[i];
  sums[t] = s;
  __syncthreads();
  for (int off = 1; off < 1024; off <<= 1) {
    int v = (t >= off) ? sums[t - off] : 0;
    __syncthreads();
    sums[t] += v;
    __syncthreads();
  }
  int prefix = (t == 0) ? 0 : sums[t - 1];
  for (int i = lo; i < hi; ++i) { S[i] = prefix; prefix += F[i]; }
  if (t == 1023) S[L] = sums[1023];
}

__global__ __launch_bounds__(256) void edge_scatter_kernel(const int* __restrict__ ei,
    const int* __restrict__ S, unsigned* __restrict__ stag, int E, int Etot,
    int NB, int NBLK) {
  __shared__ int cur[NBMAX];
  int blk = blockIdx.x, t = threadIdx.x;
  for (int b = t; b < NB; b += 256) cur[b] = S[b * NBLK + blk];
  __syncthreads();
  int base = blk * EPB;
  int lim = min(EPB, Etot - base);
  for (int i = t; i < lim; i += 256) {
    int idx = base + i;
    int s, d;
    if (idx < E) { s = ei[idx]; d = ei[E + idx]; }
    else { s = idx - E; d = s; }
    int pos = atomicAdd(&cur[d >> 7], 1);
    stag[pos] = ((unsigned)(d & 127) << 17) | (unsigned)s;
  }
}

// one block per bucket: LDS degree histogram -> prefix -> scatter into contiguous window
__global__ __launch_bounds__(256) void bucket_build_kernel(const unsigned* __restrict__ stag,
    const int* __restrict__ S, int NBLK,
    int* __restrict__ rowptr, int* __restrict__ csr_src, int N) {
  __shared__ int deg[128], pfx[128], cur[128];
  int b = blockIdx.x;
  int t = threadIdx.x;
  int gbase = S[(size_t)b * NBLK];
  int gend = S[(size_t)(b + 1) * NBLK];   // b = NB-1 hits the sentinel S[L]
  int cnt = gend - gbase;
  int node0 = b << 7;
  int nn = min(128, N - node0);
  if (t < 128) deg[t] = 0;
  __syncthreads();
  const unsigned* sb = stag + gbase;
  for (int i = t; i < cnt; i += 256) atomicAdd(&deg[sb[i] >> 17], 1);
  __syncthreads();
  if (t == 0) {
    int run = 0;
#pragma unroll 8
    for (int i = 0; i < 128; ++i) { pfx[i] = run; run += deg[i]; }
  }
  __syncthreads();
  if (t < 128) cur[t] = pfx[t];
  if (t < nn) rowptr[node0 + t] = gbase + pfx[t];
  if (b == (int)gridDim.x - 1 && t == 0) rowptr[N] = gbase + cnt;
  __syncthreads();
  for (int i = t; i < cnt; i += 256) {
    unsigned v = sb[i];
    int dl = v >> 17;
    int pos = gbase + atomicAdd(&cur[dl], 1);
    csr_src[pos] = (int)(v & 0x1ffff);
  }
}

// ---------------- input conversions ----------------

__global__ __launch_bounds__(256) void conv_x_kernel(const float* __restrict__ x,
    __hip_bfloat16* __restrict__ xb, int M, int K) {
  int idx = blockIdx.x * 256 + threadIdx.x;
  if (idx >= M * KP0) return;
  int n = idx >> 9, k = idx & (KP0 - 1);
  xb[idx] = __float2bfloat16((k < K) ? x[(size_t)n * K + k] : 0.f);
}

__global__ __launch_bounds__(256) void convT_w_kernel(const float* __restrict__ W,
    __hip_bfloat16* __restrict__ Wt, int K, int Kp) {
  int idx = blockIdx.x * 256 + threadIdx.x;
  if (idx >= 256 * Kp) return;
  int n = idx / Kp, k = idx - n * Kp;
  Wt[idx] = __float2bfloat16((k < K) ? W[(size_t)k * 256 + n] : 0.f);
}

// ---------------- bf16 MFMA GEMM (m97-style): C[M,256] = A[Mp,Kp] @ Bt[256,Kp]^T ----

__global__ __launch_bounds__(256) void gemm_mfma(const __hip_bfloat16* __restrict__ A,
    const __hip_bfloat16* __restrict__ Bt, __hip_bfloat16* __restrict__ C,
    int M, int Kp) {
  __shared__ __align__(16) __hip_bfloat16 As[128][32];
  __shared__ __align__(16) __hip_bfloat16 Bs[128][32];
  int tid = threadIdx.x;
  int wave = tid >> 6, lane = tid & 63;
  int quad = lane >> 4, mr = lane & 15;
  int row0 = blockIdx.x * 128, col0 = blockIdx.y * 128;
  int wm = (wave & 1) * 64, wn = (wave >> 1) * 64;
  floatx4 acc[4][4] = {};

  int srow = (lane >> 2);
  int kslot = lane & 3;
  int kc = (kslot ^ (srow & 3)) * 8;

  for (int k0 = 0; k0 < Kp; k0 += 32) {
#pragma unroll
    for (int j = 0; j < 2; ++j) {
      int r = wave * 32 + j * 16 + srow;
      gl_lds16(A + (size_t)(row0 + r) * Kp + k0 + kc, &As[wave * 32 + j * 16][0]);
      gl_lds16(Bt + (size_t)(col0 + r) * Kp + k0 + kc, &Bs[wave * 32 + j * 16][0]);
    }
    __syncthreads();
    short8 af[4], bfr[4];
#pragma unroll
    for (int r = 0; r < 4; ++r) {
      int row = wm + r * 16 + mr;
      af[r] = *(const short8*)&As[row][(quad ^ (row & 3)) * 8];
      int col = wn + r * 16 + mr;
      bfr[r] = *(const short8*)&Bs[col][(quad ^ (col & 3)) * 8];
    }
#pragma unroll
    for (int r = 0; r < 4; ++r)
#pragma unroll
      for (int c = 0; c < 4; ++c)
        acc[r][c] = __builtin_amdgcn_mfma_f32_16x16x32_bf16(af[r], bfr[c], acc[r][c], 0, 0, 0);
    __syncthreads();
  }
#pragma unroll
  for (int r = 0; r < 4; ++r) {
#pragma unroll
    for (int c = 0; c < 4; ++c) {
#pragma unroll
      for (int i = 0; i < 4; ++i) {
        int row = row0 + wm + r * 16 + quad * 4 + i;
        int col = col0 + wn + c * 16 + mr;
        if (row < M) C[(size_t)row * HID + col] = __float2bfloat16(acc[r][c][i]);
      }
    }
  }
}

// ---------------- per-node attention logits (bf16 H, vectorized) ----------------

__global__ __launch_bounds__(256) void node_logits_kernel(const __hip_bfloat16* __restrict__ H,
    const float* __restrict__ a_src, const float* __restrict__ a_dst,
    float* __restrict__ en_src, float* __restrict__ en_dst, int N) {
  int idx = blockIdx.x * 256 + threadIdx.x;
  if (idx >= N * HEADS) return;
  int n = idx >> 3, h = idx & 7;
  const uint4* Hp = (const uint4*)(H + (size_t)n * HID + h * 32);
  const float* S = a_src + h * 32;
  const float* D = a_dst + h * 32;
  float es = 0.f, ed = 0.f;
#pragma unroll
  for (int j = 0; j < 4; ++j) {
    uint4 u = Hp[j];
    unsigned w[4] = {u.x, u.y, u.z, u.w};
#pragma unroll
    for (int p = 0; p < 4; ++p) {
      float lo = __uint_as_float(w[p] << 16);
      float hi = __uint_as_float(w[p] & 0xffff0000u);
      int c = j * 8 + p * 2;
      es += lo * S[c] + hi * S[c + 1];
      ed += lo * D[c] + hi * D[c + 1];
    }
  }
  en_src[idx] = es;
  en_dst[idx] = ed;
}

// ---------------- fused stats + aggregation: one wave per dst node ----------------

__global__ __launch_bounds__(256) void gat_agg_kernel(const __hip_bfloat16* __restrict__ H,
    const float* __restrict__ en_src, const float* __restrict__ en_dst,
    const int* __restrict__ rowptr, const int* __restrict__ csr_src,
    const float* __restrict__ bias, float* __restrict__ out,
    __hip_bfloat16* __restrict__ hb, int apply_elu, int N) {
  int wave = threadIdx.x >> 6;
  int lane = threadIdx.x & 63;
  int n = blockIdx.x * 4 + wave;
  if (n >= N) return;
  int h = lane >> 3;
  int slot = lane & 7;
  int beg = rowptr[n], end = rowptr[n + 1];
  float ed = en_dst[n * HEADS + h];

  float m = -1e30f, s = 0.f;
  for (int e = beg + slot; e < end; e += 8) {
    int src = csr_src[e];
    float v = en_src[src * HEADS + h] + ed;
    v = (v > 0.f) ? v : 0.2f * v;
    float mn = fmaxf(m, v);
    s = s * __expf(m - mn) + __expf(v - mn);
    m = mn;
  }
#pragma unroll
  for (int off = 1; off < 8; off <<= 1) {
    float mo = __shfl_xor(m, off);
    float so = __shfl_xor(s, off);
    float mn = fmaxf(m, mo);
    s = s * __expf(m - mn) + so * __expf(mo - mn);
    m = mn;
  }
  float rs = 1.f / (s + 1e-16f);

  float4 acc = {0.f, 0.f, 0.f, 0.f};
  const __hip_bfloat16* Hc = H + lane * 4;
  for (int cs = beg; cs < end; cs += 64) {
    int cnt = min(64, end - cs);
    int myidx = csr_src[cs + ((lane < cnt) ? lane : (cnt - 1))];
    int i = 0;
    for (; i + 4 <= cnt; i += 4) {
      int s0 = __shfl(myidx, i);
      int s1 = __shfl(myidx, i + 1);
      int s2 = __shfl(myidx, i + 2);
      int s3 = __shfl(myidx, i + 3);
      uint2 g0 = *(const uint2*)(Hc + (size_t)s0 * HID);
      uint2 g1 = *(const uint2*)(Hc + (size_t)s1 * HID);
      uint2 g2 = *(const uint2*)(Hc + (size_t)s2 * HID);
      uint2 g3 = *(const uint2*)(Hc + (size_t)s3 * HID);
      float e0 = en_src[s0 * HEADS + h];
      float e1 = en_src[s1 * HEADS + h];
      float e2 = en_src[s2 * HEADS + h];
      float e3 = en_src[s3 * HEADS + h];
      uint2 gs[4] = {g0, g1, g2, g3};
      float es4[4] = {e0, e1, e2, e3};
#pragma unroll
      for (int j = 0; j < 4; ++j) {
        float v = es4[j] + ed;
        v = (v > 0.f) ? v : 0.2f * v;
        float w = __expf(v - m) * rs;
        uint2 g = gs[j];
        acc.x += w * __uint_as_float(g.x << 16);
        acc.y += w * __uint_as_float(g.x & 0xffff0000u);
        acc.z += w * __uint_as_float(g.y << 16);
        acc.w += w * __uint_as_float(g.y & 0xffff0000u);
      }
    }
    for (; i < cnt; ++i) {
      int s0 = __shfl(myidx, i);
      uint2 g = *(const uint2*)(Hc + (size_t)s0 * HID);
      float v = en_src[s0 * HEADS + h] + ed;
      v = (v > 0.f) ? v : 0.2f * v;
      float w = __expf(v - m) * rs;
      acc.x += w * __uint_as_float(g.x << 16);
      acc.y += w * __uint_as_float(g.x & 0xffff0000u);
      acc.z += w * __uint_as_float(g.y << 16);
      acc.w += w * __uint_as_float(g.y & 0xffff0000u);
    }
  }
  float4 bv = *(const float4*)(bias + lane * 4);
  float4 o;
  o.x = acc.x + bv.x; o.y = acc.y + bv.y; o.z = acc.z + bv.z; o.w = acc.w + bv.w;
  if (apply_elu) {
    o.x = (o.x > 0.f) ? o.x : expm1f(o.x);
    o.y = (o.y > 0.f) ? o.y : expm1f(o.y);
    o.z = (o.z > 0.f) ? o.z : expm1f(o.z);
    o.w = (o.w > 0.f) ? o.w : expm1f(o.w);
  }
  *(float4*)(out + (size_t)n * HID + lane * 4) = o;
  union { __hip_bfloat16 hh[4]; uint2 u; } pk;
  pk.hh[0] = __float2bfloat16(o.x);
  pk.hh[1] = __float2bfloat16(o.y);
  pk.hh[2] = __float2bfloat16(o.z);
  pk.hh[3] = __float2bfloat16(o.w);
  *(uint2*)(hb + (size_t)n * HID + lane * 4) = pk.u;
}

// ---------------- JK max + final linear + log_softmax ----------------

__global__ __launch_bounds__(256) void final_kernel(const float* __restrict__ h0,
    const float* __restrict__ h1, const float* __restrict__ h2,
    const float* __restrict__ Wf, const float* __restrict__ bf,
    float* __restrict__ out, int N) {
  __shared__ float Wfs[HID * 40];
  __shared__ float jks[4][HID];
  int tid = threadIdx.x;
  for (int i = tid; i < HID * 40; i += 256) Wfs[i] = Wf[i];
  int sub = tid >> 6, lane = tid & 63;
  int n = blockIdx.x * 4 + sub;
  if (n < N) {
    const float4* p0 = (const float4*)(h0 + (size_t)n * HID);
    const float4* p1 = (const float4*)(h1 + (size_t)n * HID);
    const float4* p2 = (const float4*)(h2 + (size_t)n * HID);
    float4 a = p0[lane], b = p1[lane], cc = p2[lane];
    float4 r;
    r.x = fmaxf(fmaxf(a.x, b.x), cc.x);
    r.y = fmaxf(fmaxf(a.y, b.y), cc.y);
    r.z = fmaxf(fmaxf(a.z, b.z), cc.z);
    r.w = fmaxf(fmaxf(a.w, b.w), cc.w);
    *(float4*)&jks[sub][lane * 4] = r;
  }
  __syncthreads();
  float logit = -INFINITY;
  if (lane < 40 && n < N) {
    float accv = bf[lane];
#pragma unroll 8
    for (int k = 0; k < HID; ++k) accv += jks[sub][k] * Wfs[k * 40 + lane];
    logit = accv;
  }
  float mx = logit;
#pragma unroll
  for (int off = 32; off > 0; off >>= 1) mx = fmaxf(mx, __shfl_down(mx, off));
  mx = __shfl(mx, 0);
  float ex = (lane < 40 && n < N) ? __expf(logit - mx) : 0.f;
  float sm = ex;
#pragma unroll
  for (int off = 32; off > 0; off >>= 1) sm += __shfl_down(sm, off);
  sm = __shfl(sm, 0);
  if (lane < 40 && n < N) out[(size_t)n * 40 + lane] = logit - mx - __logf(sm);
}

// ---------------- launch ----------------

extern "C" void kernel_launch(void* const* d_in, const int* in_sizes, int n_in,
                              void* d_out, int out_size, void* d_ws, size_t ws_size,
                              hipStream_t stream) {
  (void)n_in; (void)out_size; (void)ws_size;
  const float* x   = (const float*)d_in[0];
  const int*   ei  = (const int*)d_in[1];
  const float* W0  = (const float*)d_in[2];
  const float* as0 = (const float*)d_in[3];
  const float* ad0 = (const float*)d_in[4];
  const float* b0  = (const float*)d_in[5];
  const float* W1  = (const float*)d_in[6];
  const float* as1 = (const float*)d_in[7];
  const float* ad1 = (const float*)d_in[8];
  const float* b1  = (const float*)d_in[9];
  const float* W2  = (const float*)d_in[10];
  const float* as2 = (const float*)d_in[11];
  const float* ad2 = (const float*)d_in[12];
  const float* b2  = (const float*)d_in[13];
  const float* Wf  = (const float*)d_in[14];
  const float* bf  = (const float*)d_in[15];
  float* out = (float*)d_out;

  const int E = in_sizes[1] / 2;
  const int IN_CH = in_sizes[2] / HID;      // 500
  const int N = in_sizes[0] / IN_CH;        // 100000
  const int Etot = E + N;
  const int Mp = ((N + 127) / 128) * 128;   // 100096
  const int NB = (N + 127) >> 7;            // 782 buckets of 128 dst nodes
  const int NBLK = (Etot + EPB - 1) / EPB;  // ~202 partition blocks
  const int L = NB * NBLK;
  const size_t NM = (size_t)N * HID;

  __hip_bfloat16* xb  = (__hip_bfloat16*)d_ws;            // Mp*KP0
  __hip_bfloat16* Htb = xb + (size_t)Mp * KP0;            // N*HID
  __hip_bfloat16* hb  = Htb + NM;                         // Mp*HID
  __hip_bfloat16* Wt0 = hb + (size_t)Mp * HID;            // 256*KP0
  __hip_bfloat16* Wt1 = Wt0 + 256 * KP0;                  // 256*256
  __hip_bfloat16* Wt2 = Wt1 + 256 * 256;
  float* fbase = (float*)(Wt2 + 256 * 256);
  float* h0   = fbase;
  float* h1   = fbase + NM;
  float* h2   = fbase + 2 * NM;
  float* en_s = fbase + 3 * NM;
  float* en_d = en_s + (size_t)N * HEADS;
  int* rowptr  = (int*)(en_d + (size_t)N * HEADS);        // N+1
  int* csr_src = rowptr + (N + 1);                        // Etot
  int* F       = csr_src + Etot;                          // L
  int* S       = F + L;                                   // L+1
  unsigned* stag = (unsigned*)(S + L + 1);                // Etot

  edge_hist_kernel<<<NBLK, 256, 0, stream>>>(ei, F, E, Etot, NB, NBLK);
  scanF_kernel<<<1, 1024, 0, stream>>>(F, S, L);
  edge_scatter_kernel<<<NBLK, 256, 0, stream>>>(ei, S, stag, E, Etot, NB, NBLK);
  bucket_build_kernel<<<NB, 256, 0, stream>>>(stag, S, NBLK, rowptr, csr_src, N);

  conv_x_kernel<<<((size_t)N * KP0 + 255) / 256, 256, 0, stream>>>(x, xb, N, IN_CH);
  convT_w_kernel<<<(256 * KP0 + 255) / 256, 256, 0, stream>>>(W0, Wt0, IN_CH, KP0);
  convT_w_kernel<<<(256 * 256 + 255) / 256, 256, 0, stream>>>(W1, Wt1, HID, HID);
  convT_w_kernel<<<(256 * 256 + 255) / 256, 256, 0, stream>>>(W2, Wt2, HID, HID);

  dim3 ggrid(Mp / 128, 2);
  int lblocks = (N * HEADS + 255) / 256;
  int ablocks = (N + 3) / 4;

  // layer 0
  gemm_mfma<<<ggrid, 256, 0, stream>>>(xb, Wt0, Htb, N, KP0);
  node_logits_kernel<<<lblocks, 256, 0, stream>>>(Htb, as0, ad0, en_s, en_d, N);
  gat_agg_kernel<<<ablocks, 256, 0, stream>>>(Htb, en_s, en_d, rowptr, csr_src, b0, h0, hb, 1, N);
  // layer 1
  gemm_mfma<<<ggrid, 256, 0, stream>>>(hb, Wt1, Htb, N, HID);
  node_logits_kernel<<<lblocks, 256, 0, stream>>>(Htb, as1, ad1, en_s, en_d, N);
  gat_agg_kernel<<<ablocks, 256, 0, stream>>>(Htb, en_s, en_d, rowptr, csr_src, b1, h1, hb, 1, N);
  // layer 2
  gemm_mfma<<<ggrid, 256, 0, stream>>>(hb, Wt2, Htb, N, HID);
  node_logits_kernel<<<lblocks, 256, 0, stream>>>(Htb, as2, ad2, en_s, en_d, N);
  gat_agg_kernel<<<ablocks, 256, 0, stream>>>(Htb, en_s, en_d, rowptr, csr_src, b2, h2, hb, 0, N);

  final_kernel<<<(N + 3) / 4, 256, 0, stream>>>(h0, h1, h2, Wf, bf, out, N);
}

// Round 4
// 1771.791 us; speedup vs baseline: 1.4322x; 1.1619x over previous
//
#include <hip/hip_runtime.h>
#include <hip/hip_bf16.h>
#include <math.h>

#define HID 256
#define HEADS 8
#define KP0 512
#define EPB 16384      // edges per block in hist/scatter passes
#define NBMAX 1024     // max buckets (N/128 = 782 here)

typedef __attribute__((ext_vector_type(8))) short short8;
typedef __attribute__((ext_vector_type(4))) float floatx4;

__device__ __forceinline__ void gl_lds16(const void* g, void* l) {
  __builtin_amdgcn_global_load_lds(
      (const __attribute__((address_space(1))) void*)g,
      (__attribute__((address_space(3))) void*)l, 16, 0, 0);
}

// ---------------- contention-free bucketed CSR build ----------------
// bucket b = dst >> 7 (128 nodes/bucket). Two-pass counting sort:
// per-block LDS histograms -> hierarchical coalesced scan (bucket-major,
// block-minor) -> scatter into private ranges (no global atomics anywhere).

__global__ __launch_bounds__(256) void edge_hist_kernel(const int* __restrict__ ei,
    int* __restrict__ F, int E, int Etot, int NB, int NBLK) {
  __shared__ int hist[NBMAX];
  int blk = blockIdx.x, t = threadIdx.x;
  for (int i = t; i < NBMAX; i += 256) hist[i] = 0;
  __syncthreads();
  int base = blk * EPB;
  int lim = min(EPB, Etot - base);
  for (int i = t; i < lim; i += 256) {
    int idx = base + i;
    int d = (idx < E) ? ei[E + idx] : (idx - E);
    atomicAdd(&hist[d >> 7], 1);
  }
  __syncthreads();
  for (int b = t; b < NB; b += 256) F[b * NBLK + blk] = hist[b];
}

// hierarchical scan over F[L] -> exclusive S[L] + sentinel S[L]=total.
// 1024 elems per block, int4 coalesced.

__global__ __launch_bounds__(256) void scan_part_kernel(const int* __restrict__ F,
    int* __restrict__ bsum, int L) {
  __shared__ int ws[4];
  int blk = blockIdx.x, t = threadIdx.x;
  int base = blk * 1024 + t * 4;
  int s = 0;
  if (base + 3 < L) {
    int4 v = *(const int4*)(F + base);
    s = v.x + v.y + v.z + v.w;
  } else {
    for (int i = 0; i < 4; ++i) if (base + i < L) s += F[base + i];
  }
#pragma unroll
  for (int off = 1; off < 64; off <<= 1) s += __shfl_xor(s, off);
  if ((t & 63) == 0) ws[t >> 6] = s;
  __syncthreads();
  if (t == 0) bsum[blk] = ws[0] + ws[1] + ws[2] + ws[3];
}

__global__ __launch_bounds__(256) void scan_bsum_kernel(const int* __restrict__ bsum,
    int* __restrict__ bb, int* __restrict__ S, int NBS, int L) {
  __shared__ int ps[256];
  int t = threadIdx.x;
  int v = (t < NBS) ? bsum[t] : 0;
  ps[t] = v;
  __syncthreads();
  for (int off = 1; off < 256; off <<= 1) {
    int add = (t >= off) ? ps[t - off] : 0;
    __syncthreads();
    ps[t] += add;
    __syncthreads();
  }
  if (t < NBS) bb[t] = (t == 0) ? 0 : ps[t - 1];
  if (t == 255) S[L] = ps[255];
}

__global__ __launch_bounds__(256) void scan_apply_kernel(const int* __restrict__ F,
    const int* __restrict__ bb, int* __restrict__ S, int L) {
  __shared__ int ps[256];
  int blk = blockIdx.x, t = threadIdx.x;
  int base = blk * 1024 + t * 4;
  int v0 = 0, v1 = 0, v2 = 0, v3 = 0;
  if (base + 3 < L) {
    int4 w = *(const int4*)(F + base);
    v0 = w.x; v1 = w.y; v2 = w.z; v3 = w.w;
  } else {
    if (base + 0 < L) v0 = F[base + 0];
    if (base + 1 < L) v1 = F[base + 1];
    if (base + 2 < L) v2 = F[base + 2];
    if (base + 3 < L) v3 = F[base + 3];
  }
  ps[t] = v0 + v1 + v2 + v3;
  __syncthreads();
  for (int off = 1; off < 256; off <<= 1) {
    int add = (t >= off) ? ps[t - off] : 0;
    __syncthreads();
    ps[t] += add;
    __syncthreads();
  }
  int run = bb[blk] + ((t == 0) ? 0 : ps[t - 1]);
  if (base + 0 < L) S[base + 0] = run; run += v0;
  if (base + 1 < L) S[base + 1] = run; run += v1;
  if (base + 2 < L) S[base + 2] = run; run += v2;
  if (base + 3 < L) S[base + 3] = run;
}

__global__ __launch_bounds__(256) void edge_scatter_kernel(const int* __restrict__ ei,
    const int* __restrict__ S, unsigned* __restrict__ stag, int E, int Etot,
    int NB, int NBLK) {
  __shared__ int cur[NBMAX];
  int blk = blockIdx.x, t = threadIdx.x;
  for (int b = t; b < NB; b += 256) cur[b] = S[b * NBLK + blk];
  __syncthreads();
  int base = blk * EPB;
  int lim = min(EPB, Etot - base);
  for (int i = t; i < lim; i += 256) {
    int idx = base + i;
    int s, d;
    if (idx < E) { s = ei[idx]; d = ei[E + idx]; }
    else { s = idx - E; d = s; }
    int pos = atomicAdd(&cur[d >> 7], 1);
    stag[pos] = ((unsigned)(d & 127) << 17) | (unsigned)s;
  }
}

// one block per bucket: LDS degree histogram -> prefix -> scatter into contiguous window
__global__ __launch_bounds__(256) void bucket_build_kernel(const unsigned* __restrict__ stag,
    const int* __restrict__ S, int NBLK,
    int* __restrict__ rowptr, int* __restrict__ csr_src, int N) {
  __shared__ int deg[128], pfx[128], cur[128];
  int b = blockIdx.x;
  int t = threadIdx.x;
  int gbase = S[(size_t)b * NBLK];
  int gend = S[(size_t)(b + 1) * NBLK];   // b = NB-1 hits the sentinel S[L]
  int cnt = gend - gbase;
  int node0 = b << 7;
  int nn = min(128, N - node0);
  if (t < 128) deg[t] = 0;
  __syncthreads();
  const unsigned* sb = stag + gbase;
  for (int i = t; i < cnt; i += 256) atomicAdd(&deg[sb[i] >> 17], 1);
  __syncthreads();
  if (t == 0) {
    int run = 0;
#pragma unroll 8
    for (int i = 0; i < 128; ++i) { pfx[i] = run; run += deg[i]; }
  }
  __syncthreads();
  if (t < 128) cur[t] = pfx[t];
  if (t < nn) rowptr[node0 + t] = gbase + pfx[t];
  if (b == (int)gridDim.x - 1 && t == 0) rowptr[N] = gbase + cnt;
  __syncthreads();
  for (int i = t; i < cnt; i += 256) {
    unsigned v = sb[i];
    int dl = v >> 17;
    int pos = gbase + atomicAdd(&cur[dl], 1);
    csr_src[pos] = (int)(v & 0x1ffff);
  }
}

// ---------------- input conversions ----------------

// x[M][500] fp32 -> xb[M][512] bf16, 8 elems/thread, float4 loads + short8 store
__global__ __launch_bounds__(256) void conv_x_kernel(const float* __restrict__ x,
    __hip_bfloat16* __restrict__ xb, int M, int K) {
  long idx = (long)blockIdx.x * 256 + threadIdx.x;
  if (idx >= (long)M * (KP0 / 8)) return;
  int n = (int)(idx >> 6);
  int k0 = ((int)idx & 63) * 8;
  const float* xr = x + (size_t)n * K;
  float4 a = {0.f, 0.f, 0.f, 0.f}, b = {0.f, 0.f, 0.f, 0.f};
  if (k0 + 3 < K) a = *(const float4*)(xr + k0);
  else {
    if (k0 + 0 < K) a.x = xr[k0 + 0];
    if (k0 + 1 < K) a.y = xr[k0 + 1];
    if (k0 + 2 < K) a.z = xr[k0 + 2];
    if (k0 + 3 < K) a.w = xr[k0 + 3];
  }
  if (k0 + 7 < K) b = *(const float4*)(xr + k0 + 4);
  else {
    if (k0 + 4 < K) b.x = xr[k0 + 4];
    if (k0 + 5 < K) b.y = xr[k0 + 5];
    if (k0 + 6 < K) b.z = xr[k0 + 6];
    if (k0 + 7 < K) b.w = xr[k0 + 7];
  }
  union { short8 v; __hip_bfloat16 h[8]; } o;
  o.h[0] = __float2bfloat16(a.x); o.h[1] = __float2bfloat16(a.y);
  o.h[2] = __float2bfloat16(a.z); o.h[3] = __float2bfloat16(a.w);
  o.h[4] = __float2bfloat16(b.x); o.h[5] = __float2bfloat16(b.y);
  o.h[6] = __float2bfloat16(b.z); o.h[7] = __float2bfloat16(b.w);
  *(short8*)(xb + (size_t)n * KP0 + k0) = o.v;
}

__global__ __launch_bounds__(256) void convT_w_kernel(const float* __restrict__ W,
    __hip_bfloat16* __restrict__ Wt, int K, int Kp) {
  int idx = blockIdx.x * 256 + threadIdx.x;
  if (idx >= 256 * Kp) return;
  int n = idx / Kp, k = idx - n * Kp;
  Wt[idx] = __float2bfloat16((k < K) ? W[(size_t)k * 256 + n] : 0.f);
}

// ---------------- bf16 MFMA GEMM (m97-style): C[M,256] = A[Mp,Kp] @ Bt[256,Kp]^T ----

__global__ __launch_bounds__(256) void gemm_mfma(const __hip_bfloat16* __restrict__ A,
    const __hip_bfloat16* __restrict__ Bt, __hip_bfloat16* __restrict__ C,
    int M, int Kp) {
  __shared__ __align__(16) __hip_bfloat16 As[128][32];
  __shared__ __align__(16) __hip_bfloat16 Bs[128][32];
  int tid = threadIdx.x;
  int wave = tid >> 6, lane = tid & 63;
  int quad = lane >> 4, mr = lane & 15;
  int row0 = blockIdx.x * 128, col0 = blockIdx.y * 128;
  int wm = (wave & 1) * 64, wn = (wave >> 1) * 64;
  floatx4 acc[4][4] = {};

  int srow = (lane >> 2);
  int kslot = lane & 3;
  int kc = (kslot ^ (srow & 3)) * 8;

  for (int k0 = 0; k0 < Kp; k0 += 32) {
#pragma unroll
    for (int j = 0; j < 2; ++j) {
      int r = wave * 32 + j * 16 + srow;
      gl_lds16(A + (size_t)(row0 + r) * Kp + k0 + kc, &As[wave * 32 + j * 16][0]);
      gl_lds16(Bt + (size_t)(col0 + r) * Kp + k0 + kc, &Bs[wave * 32 + j * 16][0]);
    }
    __syncthreads();
    short8 af[4], bfr[4];
#pragma unroll
    for (int r = 0; r < 4; ++r) {
      int row = wm + r * 16 + mr;
      af[r] = *(const short8*)&As[row][(quad ^ (row & 3)) * 8];
      int col = wn + r * 16 + mr;
      bfr[r] = *(const short8*)&Bs[col][(quad ^ (col & 3)) * 8];
    }
#pragma unroll
    for (int r = 0; r < 4; ++r)
#pragma unroll
      for (int c = 0; c < 4; ++c)
        acc[r][c] = __builtin_amdgcn_mfma_f32_16x16x32_bf16(af[r], bfr[c], acc[r][c], 0, 0, 0);
    __syncthreads();
  }
#pragma unroll
  for (int r = 0; r < 4; ++r) {
#pragma unroll
    for (int c = 0; c < 4; ++c) {
#pragma unroll
      for (int i = 0; i < 4; ++i) {
        int row = row0 + wm + r * 16 + quad * 4 + i;
        int col = col0 + wn + c * 16 + mr;
        if (row < M) C[(size_t)row * HID + col] = __float2bfloat16(acc[r][c][i]);
      }
    }
  }
}

// ---------------- per-node attention logits (bf16 H, vectorized) ----------------

__global__ __launch_bounds__(256) void node_logits_kernel(const __hip_bfloat16* __restrict__ H,
    const float* __restrict__ a_src, const float* __restrict__ a_dst,
    float* __restrict__ en_src, float* __restrict__ en_dst, int N) {
  int idx = blockIdx.x * 256 + threadIdx.x;
  if (idx >= N * HEADS) return;
  int n = idx >> 3, h = idx & 7;
  const uint4* Hp = (const uint4*)(H + (size_t)n * HID + h * 32);
  const float* S = a_src + h * 32;
  const float* D = a_dst + h * 32;
  float es = 0.f, ed = 0.f;
#pragma unroll
  for (int j = 0; j < 4; ++j) {
    uint4 u = Hp[j];
    unsigned w[4] = {u.x, u.y, u.z, u.w};
#pragma unroll
    for (int p = 0; p < 4; ++p) {
      float lo = __uint_as_float(w[p] << 16);
      float hi = __uint_as_float(w[p] & 0xffff0000u);
      int c = j * 8 + p * 2;
      es += lo * S[c] + hi * S[c + 1];
      ed += lo * D[c] + hi * D[c + 1];
    }
  }
  en_src[idx] = es;
  en_dst[idx] = ed;
}

// ---------------- fused stats + aggregation: one wave per dst node ----------------

__global__ __launch_bounds__(256) void gat_agg_kernel(const __hip_bfloat16* __restrict__ H,
    const float* __restrict__ en_src, const float* __restrict__ en_dst,
    const int* __restrict__ rowptr, const int* __restrict__ csr_src,
    const float* __restrict__ bias, float* __restrict__ out,
    __hip_bfloat16* __restrict__ hb, int apply_elu, int N) {
  int wave = threadIdx.x >> 6;
  int lane = threadIdx.x & 63;
  int n = blockIdx.x * 4 + wave;
  if (n >= N) return;
  int h = lane >> 3;
  int slot = lane & 7;
  int beg = rowptr[n], end = rowptr[n + 1];
  float ed = en_dst[n * HEADS + h];

  float m = -1e30f, s = 0.f;
  for (int e = beg + slot; e < end; e += 8) {
    int src = csr_src[e];
    float v = en_src[src * HEADS + h] + ed;
    v = (v > 0.f) ? v : 0.2f * v;
    float mn = fmaxf(m, v);
    s = s * __expf(m - mn) + __expf(v - mn);
    m = mn;
  }
#pragma unroll
  for (int off = 1; off < 8; off <<= 1) {
    float mo = __shfl_xor(m, off);
    float so = __shfl_xor(s, off);
    float mn = fmaxf(m, mo);
    s = s * __expf(m - mn) + so * __expf(mo - mn);
    m = mn;
  }
  float rs = 1.f / (s + 1e-16f);

  float4 acc = {0.f, 0.f, 0.f, 0.f};
  const __hip_bfloat16* Hc = H + lane * 4;
  for (int cs = beg; cs < end; cs += 64) {
    int cnt = min(64, end - cs);
    int myidx = csr_src[cs + ((lane < cnt) ? lane : (cnt - 1))];
    int i = 0;
    for (; i + 4 <= cnt; i += 4) {
      int s0 = __shfl(myidx, i);
      int s1 = __shfl(myidx, i + 1);
      int s2 = __shfl(myidx, i + 2);
      int s3 = __shfl(myidx, i + 3);
      uint2 g0 = *(const uint2*)(Hc + (size_t)s0 * HID);
      uint2 g1 = *(const uint2*)(Hc + (size_t)s1 * HID);
      uint2 g2 = *(const uint2*)(Hc + (size_t)s2 * HID);
      uint2 g3 = *(const uint2*)(Hc + (size_t)s3 * HID);
      float e0 = en_src[s0 * HEADS + h];
      float e1 = en_src[s1 * HEADS + h];
      float e2 = en_src[s2 * HEADS + h];
      float e3 = en_src[s3 * HEADS + h];
      uint2 gs[4] = {g0, g1, g2, g3};
      float es4[4] = {e0, e1, e2, e3};
#pragma unroll
      for (int j = 0; j < 4; ++j) {
        float v = es4[j] + ed;
        v = (v > 0.f) ? v : 0.2f * v;
        float w = __expf(v - m) * rs;
        uint2 g = gs[j];
        acc.x += w * __uint_as_float(g.x << 16);
        acc.y += w * __uint_as_float(g.x & 0xffff0000u);
        acc.z += w * __uint_as_float(g.y << 16);
        acc.w += w * __uint_as_float(g.y & 0xffff0000u);
      }
    }
    for (; i < cnt; ++i) {
      int s0 = __shfl(myidx, i);
      uint2 g = *(const uint2*)(Hc + (size_t)s0 * HID);
      float v = en_src[s0 * HEADS + h] + ed;
      v = (v > 0.f) ? v : 0.2f * v;
      float w = __expf(v - m) * rs;
      acc.x += w * __uint_as_float(g.x << 16);
      acc.y += w * __uint_as_float(g.x & 0xffff0000u);
      acc.z += w * __uint_as_float(g.y << 16);
      acc.w += w * __uint_as_float(g.y & 0xffff0000u);
    }
  }
  float4 bv = *(const float4*)(bias + lane * 4);
  float4 o;
  o.x = acc.x + bv.x; o.y = acc.y + bv.y; o.z = acc.z + bv.z; o.w = acc.w + bv.w;
  if (apply_elu) {
    o.x = (o.x > 0.f) ? o.x : expm1f(o.x);
    o.y = (o.y > 0.f) ? o.y : expm1f(o.y);
    o.z = (o.z > 0.f) ? o.z : expm1f(o.z);
    o.w = (o.w > 0.f) ? o.w : expm1f(o.w);
  }
  *(float4*)(out + (size_t)n * HID + lane * 4) = o;
  union { __hip_bfloat16 hh[4]; uint2 u; } pk;
  pk.hh[0] = __float2bfloat16(o.x);
  pk.hh[1] = __float2bfloat16(o.y);
  pk.hh[2] = __float2bfloat16(o.z);
  pk.hh[3] = __float2bfloat16(o.w);
  *(uint2*)(hb + (size_t)n * HID + lane * 4) = pk.u;
}

// ---------------- JK max + final linear + log_softmax ----------------

__global__ __launch_bounds__(256) void final_kernel(const float* __restrict__ h0,
    const float* __restrict__ h1, const float* __restrict__ h2,
    const float* __restrict__ Wf, const float* __restrict__ bf,
    float* __restrict__ out, int N) {
  __shared__ float Wfs[HID * 40];
  __shared__ float jks[4][HID];
  int tid = threadIdx.x;
  for (int i = tid; i < HID * 40; i += 256) Wfs[i] = Wf[i];
  int sub = tid >> 6, lane = tid & 63;
  int n = blockIdx.x * 4 + sub;
  if (n < N) {
    const float4* p0 = (const float4*)(h0 + (size_t)n * HID);
    const float4* p1 = (const float4*)(h1 + (size_t)n * HID);
    const float4* p2 = (const float4*)(h2 + (size_t)n * HID);
    float4 a = p0[lane], b = p1[lane], cc = p2[lane];
    float4 r;
    r.x = fmaxf(fmaxf(a.x, b.x), cc.x);
    r.y = fmaxf(fmaxf(a.y, b.y), cc.y);
    r.z = fmaxf(fmaxf(a.z, b.z), cc.z);
    r.w = fmaxf(fmaxf(a.w, b.w), cc.w);
    *(float4*)&jks[sub][lane * 4] = r;
  }
  __syncthreads();
  float logit = -INFINITY;
  if (lane < 40 && n < N) {
    float accv = bf[lane];
#pragma unroll 8
    for (int k = 0; k < HID; ++k) accv += jks[sub][k] * Wfs[k * 40 + lane];
    logit = accv;
  }
  float mx = logit;
#pragma unroll
  for (int off = 32; off > 0; off >>= 1) mx = fmaxf(mx, __shfl_down(mx, off));
  mx = __shfl(mx, 0);
  float ex = (lane < 40 && n < N) ? __expf(logit - mx) : 0.f;
  float sm = ex;
#pragma unroll
  for (int off = 32; off > 0; off >>= 1) sm += __shfl_down(sm, off);
  sm = __shfl(sm, 0);
  if (lane < 40 && n < N) out[(size_t)n * 40 + lane] = logit - mx - __logf(sm);
}

// ---------------- launch ----------------

extern "C" void kernel_launch(void* const* d_in, const int* in_sizes, int n_in,
                              void* d_out, int out_size, void* d_ws, size_t ws_size,
                              hipStream_t stream) {
  (void)n_in; (void)out_size; (void)ws_size;
  const float* x   = (const float*)d_in[0];
  const int*   ei  = (const int*)d_in[1];
  const float* W0  = (const float*)d_in[2];
  const float* as0 = (const float*)d_in[3];
  const float* ad0 = (const float*)d_in[4];
  const float* b0  = (const float*)d_in[5];
  const float* W1  = (const float*)d_in[6];
  const float* as1 = (const float*)d_in[7];
  const float* ad1 = (const float*)d_in[8];
  const float* b1  = (const float*)d_in[9];
  const float* W2  = (const float*)d_in[10];
  const float* as2 = (const float*)d_in[11];
  const float* ad2 = (const float*)d_in[12];
  const float* b2  = (const float*)d_in[13];
  const float* Wf  = (const float*)d_in[14];
  const float* bf  = (const float*)d_in[15];
  float* out = (float*)d_out;

  const int E = in_sizes[1] / 2;
  const int IN_CH = in_sizes[2] / HID;      // 500
  const int N = in_sizes[0] / IN_CH;        // 100000
  const int Etot = E + N;
  const int Mp = ((N + 127) / 128) * 128;   // 100096
  const int NB = (N + 127) >> 7;            // 782 buckets of 128 dst nodes
  const int NBLK = (Etot + EPB - 1) / EPB;  // ~202 partition blocks
  const int L = NB * NBLK;
  const int NBS = (L + 1023) / 1024;        // 155 scan blocks (must be <= 256)
  const size_t NM = (size_t)N * HID;

  __hip_bfloat16* xb  = (__hip_bfloat16*)d_ws;            // Mp*KP0
  __hip_bfloat16* Htb = xb + (size_t)Mp * KP0;            // N*HID
  __hip_bfloat16* hb  = Htb + NM;                         // Mp*HID
  __hip_bfloat16* Wt0 = hb + (size_t)Mp * HID;            // 256*KP0
  __hip_bfloat16* Wt1 = Wt0 + 256 * KP0;                  // 256*256
  __hip_bfloat16* Wt2 = Wt1 + 256 * 256;
  float* fbase = (float*)(Wt2 + 256 * 256);
  float* h0   = fbase;
  float* h1   = fbase + NM;
  float* h2   = fbase + 2 * NM;
  float* en_s = fbase + 3 * NM;
  float* en_d = en_s + (size_t)N * HEADS;
  // int arrays, each start rounded up to 16B
  int* rowptr  = (int*)(en_d + (size_t)N * HEADS);        // N+1
  int* csr_src = rowptr + (((size_t)N + 1 + 3) & ~(size_t)3);   // Etot
  int* F       = csr_src + (((size_t)Etot + 3) & ~(size_t)3);   // L
  int* S       = F + (((size_t)L + 3) & ~(size_t)3);            // L+1
  int* bsum    = S + (((size_t)L + 1 + 3) & ~(size_t)3);        // NBS
  int* bb      = bsum + 256;                                    // NBS
  unsigned* stag = (unsigned*)(bb + 256);                       // Etot

  edge_hist_kernel<<<NBLK, 256, 0, stream>>>(ei, F, E, Etot, NB, NBLK);
  scan_part_kernel<<<NBS, 256, 0, stream>>>(F, bsum, L);
  scan_bsum_kernel<<<1, 256, 0, stream>>>(bsum, bb, S, NBS, L);
  scan_apply_kernel<<<NBS, 256, 0, stream>>>(F, bb, S, L);
  edge_scatter_kernel<<<NBLK, 256, 0, stream>>>(ei, S, stag, E, Etot, NB, NBLK);
  bucket_build_kernel<<<NB, 256, 0, stream>>>(stag, S, NBLK, rowptr, csr_src, N);

  conv_x_kernel<<<((size_t)N * (KP0 / 8) + 255) / 256, 256, 0, stream>>>(x, xb, N, IN_CH);
  convT_w_kernel<<<(256 * KP0 + 255) / 256, 256, 0, stream>>>(W0, Wt0, IN_CH, KP0);
  convT_w_kernel<<<(256 * 256 + 255) / 256, 256, 0, stream>>>(W1, Wt1, HID, HID);
  convT_w_kernel<<<(256 * 256 + 255) / 256, 256, 0, stream>>>(W2, Wt2, HID, HID);

  dim3 ggrid(Mp / 128, 2);
  int lblocks = (N * HEADS + 255) / 256;
  int ablocks = (N + 3) / 4;

  // layer 0
  gemm_mfma<<<ggrid, 256, 0, stream>>>(xb, Wt0, Htb, N, KP0);
  node_logits_kernel<<<lblocks, 256, 0, stream>>>(Htb, as0, ad0, en_s, en_d, N);
  gat_agg_kernel<<<ablocks, 256, 0, stream>>>(Htb, en_s, en_d, rowptr, csr_src, b0, h0, hb, 1, N);
  // layer 1
  gemm_mfma<<<ggrid, 256, 0, stream>>>(hb, Wt1, Htb, N, HID);
  node_logits_kernel<<<lblocks, 256, 0, stream>>>(Htb, as1, ad1, en_s, en_d, N);
  gat_agg_kernel<<<ablocks, 256, 0, stream>>>(Htb, en_s, en_d, rowptr, csr_src, b1, h1, hb, 1, N);
  // layer 2
  gemm_mfma<<<ggrid, 256, 0, stream>>>(hb, Wt2, Htb, N, HID);
  node_logits_kernel<<<lblocks, 256, 0, stream>>>(Htb, as2, ad2, en_s, en_d, N);
  gat_agg_kernel<<<ablocks, 256, 0, stream>>>(Htb, en_s, en_d, rowptr, csr_src, b2, h2, hb, 0, N);

  final_kernel<<<(N + 3) / 4, 256, 0, stream>>>(h0, h1, h2, Wf, bf, out, N);
}